// Round 2
// baseline (1152.149 us; speedup 1.0000x reference)
//
#include <hip/hip_runtime.h>
#include <hip/hip_bf16.h>

#define H    224
#define HW   50176        // 224*224
#define KCUT 56
#define JH   112          // j-half per block
#define LDSRS 464         // padded LDS row stride in bytes (29*16: odd multiple of 16
                          //  -> rows rotate over all 8 bank-quads, bijective, aligned)
#define LDSB (JH * LDSRS) // 51968 B per R1T buffer
#define LDS_BYTES (2 * LDSB)   // 103936 B total (dynamic LDS; 1 block/CU)

// ws float offsets (total ~0.4 MB)
#define OFF_D  0
#define OFF_M  50176      // bf16 M, 50176 el = 25088 floats
#define OFF_P  (OFF_M + 25088)

#define DPI 3.14159265358979323846

typedef __attribute__((ext_vector_type(8))) short short8;   // 8 bf16 = 4 VGPR
typedef __attribute__((ext_vector_type(4))) float f32x4;

__device__ __forceinline__ f32x4 mfma_bf16(short8 a, short8 b, f32x4 c) {
    return __builtin_amdgcn_mfma_f32_16x16x32_bf16(a, b, c, 0, 0, 0);
}

__device__ __forceinline__ short bf16b(float f) {
    __hip_bfloat16 h = __float2bfloat16(f);
    return *reinterpret_cast<short*>(&h);
}

// 8 fp32 -> short8 of bf16 (two float4 loads, RNE cvt — same rounding as the
// previously verified kernel's staging conversion)
__device__ __forceinline__ short8 cvt8(const float* p) {
    const float4 v0 = *(const float4*)p;
    const float4 v1 = *(const float4*)(p + 4);
    short8 r;
    r[0] = bf16b(v0.x); r[1] = bf16b(v0.y); r[2] = bf16b(v0.z); r[3] = bf16b(v0.w);
    r[4] = bf16b(v1.x); r[5] = bf16b(v1.y); r[6] = bf16b(v1.z); r[7] = bf16b(v1.w);
    return r;
}

__global__ void k_build_D(float* __restrict__ D) {
    int idx = blockIdx.x * 256 + threadIdx.x;
    if (idx >= HW) return;
    int k = idx / H, i = idx - k * H;
    double v = cos(DPI * (2.0 * i + 1.0) * (double)k / (2.0 * H)) * sqrt(2.0 / H);
    if (k == 0) v *= 0.70710678118654752440;
    D[idx] = (float)v;
}

__global__ void k_build_MP(const float* __restrict__ D,
                           __hip_bfloat16* __restrict__ Mb,
                           __hip_bfloat16* __restrict__ Pb) {
    int idx = blockIdx.x * 256 + threadIdx.x;
    if (idx >= HW) return;
    int i = idx / H, j = idx - i * H;
    float m = 0.f, p = 0.f;
    for (int k = 0; k < H; ++k) {
        float t = D[i * H + k] * D[k * H + j];
        m += t;
        if (k < KCUT) p += t;
    }
    Mb[idx] = __float2bfloat16(m);
    Pb[idx] = __float2bfloat16(p);
}

// Fused per-half-slice kernel: one block owns slice p, output columns [j0b, j0b+112).
// Phase 1: R1T[jj,k] = sum_t x[k,t]*M[j0b+jj,t]  (and -R1pT with P, pre-negated) -> LDS.
// Phase 2: out[i,j] = x[i,j] * sum_k ( M[i,k]*R1T[jj,k] + P[i,k]*R1pT[jj,k] ).
// All operand fetches are direct global->VGPR fragment loads (M/P are L2-hot,
// x is read 2x and mostly L2-absorbed). The intermediate never leaves LDS.
__global__ __launch_bounds__(448, 2)
void k_fused(const float* __restrict__ X,
             const __hip_bfloat16* __restrict__ Mb,
             const __hip_bfloat16* __restrict__ Pb,
             float* __restrict__ Out)
{
    extern __shared__ __align__(16) char lds[];   // [2][112][464B]: R1T then R1pT

    // block decode with XCD co-location of the two halves of a slice:
    // default dispatch round-robins blockIdx%8 across XCDs; invert it so the
    // pair (p,0),(p,1) lands on one XCD and shares the x-slice in that L2.
    const int Bid = blockIdx.x;                 // 0..3071  (= 8 * 384)
    const int xcd = Bid & 7, ix = Bid >> 3;     // ix: 0..383
    const int p   = xcd * 192 + (ix >> 1);      // slice 0..1535 (bijective)
    const int j0b = (ix & 1) * JH;
    const float* x  = X   + (size_t)p * HW;
    float*      out = Out + (size_t)p * HW;

    const int t = threadIdx.x;
    const int w = t >> 6, l = t & 63;           // 7 waves
    const int col = l & 15, q = l >> 4;
    const int koff = q * 8;

    // ---------------- phase 1: dual GEMM1 into LDS (transposed write) -------
    f32x4 acc[2][14];
    #pragma unroll
    for (int i = 0; i < 2; ++i)
        #pragma unroll
        for (int j = 0; j < 14; ++j) acc[i][j] = (f32x4)0.f;

    const float* xa0 = x + (size_t)(32 * w + col) * H + koff;   // A rows: x rows k
    const float* xa1 = xa0 + 16 * H;
    const __hip_bfloat16* Mj = Mb + (size_t)(j0b + col) * H + koff;  // B rows: M[j-half]
    const __hip_bfloat16* Pj = Pb + (size_t)(j0b + col) * H + koff;

    #pragma unroll 1
    for (int ks = 0; ks < 7; ++ks) {
        const int k0 = ks * 32;
        const short8 a0 = cvt8(xa0 + k0);
        const short8 a1 = cvt8(xa1 + k0);
        #pragma unroll
        for (int nt = 0; nt < 7; ++nt) {
            const short8 b = *(const short8*)(Mj + nt * 16 * H + k0);
            acc[0][nt] = mfma_bf16(a0, b, acc[0][nt]);
            acc[1][nt] = mfma_bf16(a1, b, acc[1][nt]);
        }
        #pragma unroll
        for (int nt = 0; nt < 7; ++nt) {
            const short8 b = *(const short8*)(Pj + nt * 16 * H + k0);
            acc[0][7 + nt] = mfma_bf16(a0, b, acc[0][7 + nt]);
            acc[1][7 + nt] = mfma_bf16(a1, b, acc[1][7 + nt]);
        }
    }

    // epilogue: C rows (m = k, 4 consecutive per lane) -> contiguous k in R1T[jj][k]
    #pragma unroll
    for (int im = 0; im < 2; ++im) {
        const int kk2 = (32 * w + 16 * im + 4 * q) * 2;   // k byte offset (mult of 8)
        #pragma unroll
        for (int nt = 0; nt < 14; ++nt) {
            const int jj   = (nt < 7 ? nt : nt - 7) * 16 + col;
            const int base = (nt < 7 ? 0 : LDSB);
            const float sgn = (nt < 7 ? 1.f : -1.f);      // pre-negate P part: o = y - z
            short t4[4];
            #pragma unroll
            for (int r = 0; r < 4; ++r) t4[r] = bf16b(sgn * acc[im][nt][r]);
            *(uint2*)(lds + base + jj * LDSRS + kk2) = *(uint2*)t4;
        }
    }

    __syncthreads();   // the only barrier in the kernel

    // ---------------- phase 2: out = x * (M.R1 - P.R1p), K=448 fused acc ----
    f32x4 o[14];
    #pragma unroll
    for (int j = 0; j < 14; ++j) o[j] = (f32x4)0.f;

    const int jj = 16 * w + col;                            // A rows: R1T rows (m = j)
    const __hip_bfloat16* Mi = Mb + (size_t)col * H + koff; // B rows: M rows i (full 224)
    const __hip_bfloat16* Pi = Pb + (size_t)col * H + koff;

    #pragma unroll 1
    for (int ks = 0; ks < 7; ++ks) {
        const int k0 = ks * 32;
        const short8 a = *(const short8*)(lds + jj * LDSRS + (k0 + koff) * 2);
        #pragma unroll
        for (int it = 0; it < 14; ++it) {
            const short8 b = *(const short8*)(Mi + it * 16 * H + k0);
            o[it] = mfma_bf16(a, b, o[it]);
        }
    }
    #pragma unroll 1
    for (int ks = 0; ks < 7; ++ks) {
        const int k0 = ks * 32;
        const short8 a = *(const short8*)(lds + LDSB + jj * LDSRS + (k0 + koff) * 2);
        #pragma unroll
        for (int it = 0; it < 14; ++it) {
            const short8 b = *(const short8*)(Pi + it * 16 * H + k0);
            o[it] = mfma_bf16(a, b, o[it]);
        }
    }

    // epilogue: lane holds out[i, jw..jw+3] (contiguous j) -> float4 in/out
    const int jw = j0b + 16 * w + 4 * q;
    #pragma unroll
    for (int it = 0; it < 14; ++it) {
        const int i = it * 16 + col;
        const size_t off = (size_t)i * H + jw;
        const float4 xv = *(const float4*)(x + off);
        float4 ov;
        ov.x = xv.x * o[it][0];
        ov.y = xv.y * o[it][1];
        ov.z = xv.z * o[it][2];
        ov.w = xv.w * o[it][3];
        *(float4*)(out + off) = ov;
    }
}

extern "C" void kernel_launch(void* const* d_in, const int* in_sizes, int n_in,
                              void* d_out, int out_size, void* d_ws, size_t ws_size,
                              hipStream_t stream) {
    const float* x = (const float*)d_in[0];
    float* out = (float*)d_out;
    float* w = (float*)d_ws;
    float* D = w + OFF_D;
    __hip_bfloat16* Mb = (__hip_bfloat16*)(w + OFF_M);
    __hip_bfloat16* Pb = (__hip_bfloat16*)(w + OFF_P);

    k_build_D <<<dim3((HW + 255) / 256), dim3(256), 0, stream>>>(D);
    k_build_MP<<<dim3((HW + 255) / 256), dim3(256), 0, stream>>>(D, Mb, Pb);
    // 1536 slices x 2 half-slices = 3072 blocks = exactly 12 per CU
    k_fused   <<<dim3(3072), dim3(448), LDS_BYTES, stream>>>(x, Mb, Pb, out);
}

// Round 3
// 1090.012 us; speedup vs baseline: 1.0570x; 1.0570x over previous
//
#include <hip/hip_runtime.h>
#include <hip/hip_bf16.h>

#define H    224
#define HW   50176        // 224*224
#define KCUT 56
#define JH   112          // j-half per block
#define LDSRS 464         // padded LDS row stride in bytes (29*16: odd multiple of 16
                          //  -> rows rotate over all 8 bank-quads, bijective, aligned)
#define LDSB (JH * LDSRS) // 51968 B per R1T buffer
#define LDS_BYTES (2 * LDSB)   // 103936 B total (dynamic LDS; 1 block/CU)

// ws float offsets (total ~0.4 MB)
#define OFF_D  0
#define OFF_M  50176      // bf16 M, 50176 el = 25088 floats
#define OFF_P  (OFF_M + 25088)

#define DPI 3.14159265358979323846

typedef __attribute__((ext_vector_type(8))) short short8;   // 8 bf16 = 4 VGPR
typedef __attribute__((ext_vector_type(4))) float f32x4;

__device__ __forceinline__ f32x4 mfma_bf16(short8 a, short8 b, f32x4 c) {
    return __builtin_amdgcn_mfma_f32_16x16x32_bf16(a, b, c, 0, 0, 0);
}

__device__ __forceinline__ short bf16b(float f) {
    __hip_bfloat16 h = __float2bfloat16(f);
    return *reinterpret_cast<short*>(&h);
}

// 8 fp32 -> short8 of bf16 (two float4 loads, RNE cvt)
__device__ __forceinline__ short8 cvt8(const float* p) {
    const float4 v0 = *(const float4*)p;
    const float4 v1 = *(const float4*)(p + 4);
    short8 r;
    r[0] = bf16b(v0.x); r[1] = bf16b(v0.y); r[2] = bf16b(v0.z); r[3] = bf16b(v0.w);
    r[4] = bf16b(v1.x); r[5] = bf16b(v1.y); r[6] = bf16b(v1.z); r[7] = bf16b(v1.w);
    return r;
}

__global__ void k_build_D(float* __restrict__ D) {
    int idx = blockIdx.x * 256 + threadIdx.x;
    if (idx >= HW) return;
    int k = idx / H, i = idx - k * H;
    double v = cos(DPI * (2.0 * i + 1.0) * (double)k / (2.0 * H)) * sqrt(2.0 / H);
    if (k == 0) v *= 0.70710678118654752440;
    D[idx] = (float)v;
}

// M = D*D, P = D[:,:56]*D[:56,:]  (fp32, bf16 store).
// 8 independent partial accumulators break the load->FMA dependency chain
// (old version: 224 serial dependent loads -> ~300 us; this: 8-deep ILP).
__global__ void k_build_MP(const float* __restrict__ D,
                           __hip_bfloat16* __restrict__ Mb,
                           __hip_bfloat16* __restrict__ Pb) {
    int idx = blockIdx.x * 256 + threadIdx.x;
    if (idx >= HW) return;
    int i = idx / H, j = idx - i * H;
    const float* Di = D + (size_t)i * H;   // row i, unit stride
    const float* Dj = D + j;               // col j, stride H (coalesced across lanes)
    float s0=0.f,s1=0.f,s2=0.f,s3=0.f,s4=0.f,s5=0.f,s6=0.f,s7=0.f;
    for (int k = 0; k < KCUT; k += 8) {    // 7 iters
        s0 += Di[k+0] * Dj[(size_t)(k+0)*H];
        s1 += Di[k+1] * Dj[(size_t)(k+1)*H];
        s2 += Di[k+2] * Dj[(size_t)(k+2)*H];
        s3 += Di[k+3] * Dj[(size_t)(k+3)*H];
        s4 += Di[k+4] * Dj[(size_t)(k+4)*H];
        s5 += Di[k+5] * Dj[(size_t)(k+5)*H];
        s6 += Di[k+6] * Dj[(size_t)(k+6)*H];
        s7 += Di[k+7] * Dj[(size_t)(k+7)*H];
    }
    const float p = ((s0+s1)+(s2+s3)) + ((s4+s5)+(s6+s7));
    for (int k = KCUT; k < H; k += 8) {    // 21 iters
        s0 += Di[k+0] * Dj[(size_t)(k+0)*H];
        s1 += Di[k+1] * Dj[(size_t)(k+1)*H];
        s2 += Di[k+2] * Dj[(size_t)(k+2)*H];
        s3 += Di[k+3] * Dj[(size_t)(k+3)*H];
        s4 += Di[k+4] * Dj[(size_t)(k+4)*H];
        s5 += Di[k+5] * Dj[(size_t)(k+5)*H];
        s6 += Di[k+6] * Dj[(size_t)(k+6)*H];
        s7 += Di[k+7] * Dj[(size_t)(k+7)*H];
    }
    const float m = ((s0+s1)+(s2+s3)) + ((s4+s5)+(s6+s7));
    Mb[idx] = __float2bfloat16(m);
    Pb[idx] = __float2bfloat16(p);
}

// Fused per-half-slice kernel, 14 waves (896 thr) for 3.5 waves/SIMD latency hiding.
// Phase 1: R1T[jj,k] = sum_t x[k,t]*M[j0b+jj,t]  (and -R1pT with P, pre-negated) -> LDS.
//          wave w owns m-tile rows [16w,16w+16): acc[14] (7 M-tiles + 7 P-tiles).
// Phase 2: out[i,j] = x[i,j]*sum_k( M[i,k]*R1T[jj,k] + P[i,k]*R1pT[jj,k] ).
//          wave w = (jt,ih): j-tile jt=w>>1, i-half ih=w&1: o[7] over K=448 fused.
__global__ __launch_bounds__(896, 4)   // hard 128-VGPR cap: 14 waves need 4+4+3+3/SIMD
void k_fused(const float* __restrict__ X,
             const __hip_bfloat16* __restrict__ Mb,
             const __hip_bfloat16* __restrict__ Pb,
             float* __restrict__ Out)
{
    extern __shared__ __align__(16) char lds[];   // [2][112][464B]: R1T then -R1pT

    // XCD co-location: pair (p,0),(p,1) on one XCD to share the x-slice in L2.
    const int Bid = blockIdx.x;                 // 0..3071  (= 8 * 384)
    const int xcd = Bid & 7, ix = Bid >> 3;     // ix: 0..383
    const int p   = xcd * 192 + (ix >> 1);      // slice 0..1535 (bijective)
    const int j0b = (ix & 1) * JH;
    const float* x  = X   + (size_t)p * HW;
    float*      out = Out + (size_t)p * HW;

    const int t = threadIdx.x;
    const int w = t >> 6, l = t & 63;           // 14 waves
    const int col = l & 15, q = l >> 4;
    const int koff = q * 8;

    // ---------------- phase 1: dual GEMM1 into LDS (transposed write) -------
    f32x4 acc[14];
    #pragma unroll
    for (int j = 0; j < 14; ++j) acc[j] = (f32x4)0.f;

    const float* xa = x + (size_t)(16 * w + col) * H + koff;         // A rows: x rows k
    const __hip_bfloat16* Mj = Mb + (size_t)(j0b + col) * H + koff;  // B rows: M[j-half]
    const __hip_bfloat16* Pj = Pb + (size_t)(j0b + col) * H + koff;

    #pragma unroll 1
    for (int ks = 0; ks < 7; ++ks) {
        const int k0 = ks * 32;
        const short8 a = cvt8(xa + k0);
        #pragma unroll
        for (int nt = 0; nt < 7; ++nt) {
            const short8 b = *(const short8*)(Mj + nt * 16 * H + k0);
            acc[nt] = mfma_bf16(a, b, acc[nt]);
        }
        #pragma unroll
        for (int nt = 0; nt < 7; ++nt) {
            const short8 b = *(const short8*)(Pj + nt * 16 * H + k0);
            acc[7 + nt] = mfma_bf16(a, b, acc[7 + nt]);
        }
    }

    // epilogue: C rows (k = 16w + 4q + r, contiguous per lane) -> R1T[jj][k]
    {
        const int kk2 = (16 * w + 4 * q) * 2;   // k byte offset (mult of 8)
        #pragma unroll
        for (int nt = 0; nt < 14; ++nt) {
            const int jj   = (nt < 7 ? nt : nt - 7) * 16 + col;
            const int base = (nt < 7 ? 0 : LDSB);
            const float sgn = (nt < 7 ? 1.f : -1.f);   // pre-negate P part: o = y - z
            short t4[4];
            #pragma unroll
            for (int r = 0; r < 4; ++r) t4[r] = bf16b(sgn * acc[nt][r]);
            *(uint2*)(lds + base + jj * LDSRS + kk2) = *(uint2*)t4;
        }
    }

    __syncthreads();   // the only barrier in the kernel

    // ---------------- phase 2: out = x * (M.R1 - P.R1p), K=448 fused acc ----
    f32x4 o[7];
    #pragma unroll
    for (int j = 0; j < 7; ++j) o[j] = (f32x4)0.f;

    const int jt = w >> 1, ih = w & 1;
    const int jj = 16 * jt + col;                           // A rows: R1T rows (m = j)
    const __hip_bfloat16* Mi = Mb + (size_t)(ih * JH + col) * H + koff; // B rows: i
    const __hip_bfloat16* Pi = Pb + (size_t)(ih * JH + col) * H + koff;

    #pragma unroll 1
    for (int ks = 0; ks < 7; ++ks) {
        const int k0 = ks * 32;
        const short8 a = *(const short8*)(lds + jj * LDSRS + (k0 + koff) * 2);
        #pragma unroll
        for (int it = 0; it < 7; ++it) {
            const short8 b = *(const short8*)(Mi + it * 16 * H + k0);
            o[it] = mfma_bf16(a, b, o[it]);
        }
    }
    #pragma unroll 1
    for (int ks = 0; ks < 7; ++ks) {
        const int k0 = ks * 32;
        const short8 a = *(const short8*)(lds + LDSB + jj * LDSRS + (k0 + koff) * 2);
        #pragma unroll
        for (int it = 0; it < 7; ++it) {
            const short8 b = *(const short8*)(Pi + it * 16 * H + k0);
            o[it] = mfma_bf16(a, b, o[it]);
        }
    }

    // epilogue: lane holds out[i, jw..jw+3] (contiguous j) -> float4 in/out
    const int jw = j0b + 16 * jt + 4 * q;
    #pragma unroll
    for (int it = 0; it < 7; ++it) {
        const int i = ih * JH + it * 16 + col;
        const size_t off = (size_t)i * H + jw;
        const float4 xv = *(const float4*)(x + off);
        float4 ov;
        ov.x = xv.x * o[it][0];
        ov.y = xv.y * o[it][1];
        ov.z = xv.z * o[it][2];
        ov.w = xv.w * o[it][3];
        *(float4*)(out + off) = ov;
    }
}

extern "C" void kernel_launch(void* const* d_in, const int* in_sizes, int n_in,
                              void* d_out, int out_size, void* d_ws, size_t ws_size,
                              hipStream_t stream) {
    const float* x = (const float*)d_in[0];
    float* out = (float*)d_out;
    float* w = (float*)d_ws;
    float* D = w + OFF_D;
    __hip_bfloat16* Mb = (__hip_bfloat16*)(w + OFF_M);
    __hip_bfloat16* Pb = (__hip_bfloat16*)(w + OFF_P);

    k_build_D <<<dim3((HW + 255) / 256), dim3(256), 0, stream>>>(D);
    k_build_MP<<<dim3((HW + 255) / 256), dim3(256), 0, stream>>>(D, Mb, Pb);
    // 1536 slices x 2 half-slices = 3072 blocks = exactly 12 per CU
    k_fused   <<<dim3(3072), dim3(896), LDS_BYTES, stream>>>(x, Mb, Pb, out);
}